// Round 12
// baseline (2177.962 us; speedup 1.0000x reference)
//
#include <hip/hip_runtime.h>
#include <cfloat>
#include <cstdint>

#define NV    8192
#define NM    32768
#define KNN   16
#define CIN   32
#define COUT  64
#define CPROV 96
#define SUB   256
#define CAP   8
#define MT    8      // grid points per wave in mlp kernel
#define MLP_BLOCK 1024
#define WPB   (MLP_BLOCK/64)

// ===========================================================================
// KNN: validated selection (full scan in index order, u64-key min-16,
// tau-seeded self-tightening d2-domain gate, LDS FIFO + branchless merge —
// R8/R9/R10/R11). R12: chunk count is RUNTIME (gridDim.y): 16 chunks when
// ws_size permits the 33.5MB cand buffer (-> 2048 blocks, 8 blocks/CU, full
// occupancy; R11 was grid-capped at 2 blocks/CU), else the proven 4-chunk
// layout. Hot loop = R9's LDS-broadcast (validated bit-exact twice).
// Golden d2 path (validated R4/R6/R8-R11): q=grid*32, r=vert*32; qq/rr plain
// ascending mul/add; dot = fma(q2,r2, fma(q1,r1, q0*r0));
// d2 = fmaf(-2,dot,qq+rr)  (bit-identical to (qq+rr)-2*dot; 2*dot exact).
// ===========================================================================

__device__ __forceinline__ unsigned long long d2key(float d2, unsigned int idx) {
    unsigned int b = __float_as_uint(d2);
    b ^= (b & 0x80000000u) ? 0xFFFFFFFFu : 0x80000000u;  // total-order map
    return ((unsigned long long)b << 32) | idx;
}

__device__ __forceinline__ float key_d2f(unsigned long long key) {
    unsigned int b = (unsigned int)(key >> 32);
    b = (b & 0x80000000u) ? (b ^ 0x80000000u) : ~b;      // inverse map
    return __uint_as_float(b);
}

__device__ __forceinline__ void key_insert(unsigned long long* a,
                                           unsigned long long key) {
    // branchless sorted (ascending) insert-and-drop-max
#pragma unroll
    for (int i = KNN - 1; i >= 1; --i) {
        unsigned long long hi = (a[i-1] > key) ? a[i-1] : key;
        a[i] = (hi < a[i]) ? hi : a[i];
    }
    a[0] = (key < a[0]) ? key : a[0];
}

__device__ __forceinline__ int bin_of(float x) {
    int b = (int)(x * 32.0f);
    return min(31, max(0, b));
}

__global__ __launch_bounds__(256) void bin_count_kernel(
    const float* __restrict__ verts, int* __restrict__ counts)
{
    int v = blockIdx.x * 256 + threadIdx.x;
    int bx = bin_of(verts[v * 3 + 0]);
    int by = bin_of(verts[v * 3 + 1]);
    int bz = bin_of(verts[v * 3 + 2]);
    atomicAdd(&counts[(bx * 32 + by) * 32 + bz], 1);
}

__global__ __launch_bounds__(1024) void prefix_kernel(
    const int* __restrict__ counts, int* __restrict__ prefix)
{
    __shared__ int lds[1024];
    int tid = threadIdx.x;
    int local[32]; int s = 0;
#pragma unroll
    for (int i = 0; i < 32; ++i) { local[i] = counts[tid * 32 + i]; s += local[i]; }
    lds[tid] = s; __syncthreads();
    for (int off = 1; off < 1024; off <<= 1) {
        int v = (tid >= off) ? lds[tid - off] : 0;
        __syncthreads();
        lds[tid] += v;
        __syncthreads();
    }
    int run = lds[tid] - s;
#pragma unroll
    for (int i = 0; i < 32; ++i) { prefix[tid * 32 + i] = run; run += local[i]; }
    if (tid == 1023) prefix[32768] = run;
}

// tau[m] = 3*(R+1)^2 where radius-R cell cube holds >= 16 points (validated)
__global__ __launch_bounds__(256) void radius_kernel(
    const float* __restrict__ grid_verts, const int* __restrict__ prefix,
    float* __restrict__ tau)
{
    int m = blockIdx.x * 256 + threadIdx.x;
    int bx = bin_of(grid_verts[m * 3 + 0]);
    int by = bin_of(grid_verts[m * 3 + 1]);
    int bz = bin_of(grid_verts[m * 3 + 2]);
    int R = 1;
    for (; R < 32; ++R) {
        int cnt = 0;
        int xlo = max(0, bx - R), xhi = min(31, bx + R);
        int ylo = max(0, by - R), yhi = min(31, by + R);
        int zlo = max(0, bz - R), zhi = min(31, bz + R);
        for (int x = xlo; x <= xhi; ++x)
            for (int y = ylo; y <= yhi; ++y) {
                int c = (x * 32 + y) * 32;
                cnt += prefix[c + zhi + 1] - prefix[c + zlo];
            }
        if (cnt >= KNN) break;
    }
    float Rp = (float)(R + 1);
    tau[m] = 3.0f * Rp * Rp;
}

__global__ __launch_bounds__(256, 8) void knn_partial_kernel(
    const float* __restrict__ verts,
    const float* __restrict__ grid_verts,
    const float* __restrict__ tau,
    unsigned long long* __restrict__ cand)   // (NM, nch*KNN)
{
    __shared__ float4 sv[SUB];                       // 4 KB
    __shared__ unsigned long long sbuf[CAP][256];    // 16 KB
    const int tid   = threadIdx.x;
    const int m     = blockIdx.x * 256 + tid;
    const int chunk = blockIdx.y;
    const int nch   = gridDim.y;
    const int chunklen = NV / nch;
    const int nsub  = chunklen / SUB;

    const float q0 = __fmul_rn(grid_verts[m * 3 + 0], 32.0f);
    const float q1 = __fmul_rn(grid_verts[m * 3 + 1], 32.0f);
    const float q2 = __fmul_rn(grid_verts[m * 3 + 2], 32.0f);
    const float qq = __fadd_rn(__fadd_rn(__fmul_rn(q0, q0), __fmul_rn(q1, q1)),
                               __fmul_rn(q2, q2));

    // seed = key(bound), idx 0; bound > all golden top-16 d2 (validated margin)
    const float bound = tau[m] + 0.13f;
    unsigned int bb = __float_as_uint(bound) ^ 0x80000000u;  // bound > 0
    const unsigned long long seed = ((unsigned long long)bb << 32);

    unsigned long long a[KNN];
#pragma unroll
    for (int s = 0; s < KNN; ++s) a[s] = seed;
    float gd = bound;      // d2-domain gate = d2 part of a[15]
    int cnt = 0;

    for (int sub = 0; sub < nsub; ++sub) {
        __syncthreads();
        {
            int v = chunk * chunklen + sub * SUB + tid;
            float r0 = __fmul_rn(verts[v * 3 + 0], 32.0f);
            float r1 = __fmul_rn(verts[v * 3 + 1], 32.0f);
            float r2 = __fmul_rn(verts[v * 3 + 2], 32.0f);
            float rr = __fadd_rn(__fadd_rn(__fmul_rn(r0, r0), __fmul_rn(r1, r1)),
                                 __fmul_rn(r2, r2));
            sv[tid] = make_float4(r0, r1, r2, rr);
        }
        __syncthreads();

        const unsigned int base = chunk * chunklen + sub * SUB;
        for (int t = 0; t < SUB; t += 8) {
            float d2v[8];
#pragma unroll
            for (int k = 0; k < 8; ++k) {
                float4 v = sv[t + k];
                float dot = fmaf(q2, v.z, fmaf(q1, v.y, __fmul_rn(q0, v.x)));
                d2v[k] = fmaf(-2.0f, dot, __fadd_rn(qq, v.w));
            }
#pragma unroll
            for (int k = 0; k < 8; ++k) {
                if (d2v[k] <= gd) {   // conservative gate; exact insert decides
                    unsigned long long key = d2key(d2v[k], base + t + k);
                    if (cnt < CAP) { sbuf[cnt][tid] = key; ++cnt; }
                    else {  // overflow: exact direct insert, tighten gate
                        key_insert(a, key);
                        gd = key_d2f(a[KNN - 1]);
                    }
                }
            }
        }
        // merge private FIFO (lane-private; no barrier needed)
        int mx = cnt;
#pragma unroll
        for (int off = 32; off; off >>= 1) mx = max(mx, __shfl_xor(mx, off));
        for (int k = 0; k < mx; ++k) {
            unsigned long long key = (k < cnt) ? sbuf[k][tid] : ~0ULL;
            key_insert(a, key);
        }
        if (mx) gd = key_d2f(a[KNN - 1]);
        cnt = 0;
    }

    unsigned long long* o = cand + (size_t)m * (nch * KNN) + chunk * KNN;
#pragma unroll
    for (int s = 0; s < KNN; ++s) o[s] = a[s];
}

__global__ __launch_bounds__(256) void knn_merge_kernel(
    const unsigned long long* __restrict__ cand, int* __restrict__ knn_idx,
    int nch)
{
    const int m = blockIdx.x * 256 + threadIdx.x;
    unsigned long long a[KNN];
#pragma unroll
    for (int s = 0; s < KNN; ++s) a[s] = ~0ULL;
    const int nk = nch * KNN;
    for (int k = 0; k < nk; ++k) {
        unsigned long long key = cand[(size_t)m * nk + k];
        if (key < a[KNN - 1]) key_insert(a, key);
    }
#pragma unroll
    for (int s = 0; s < KNN; ++s)
        knn_idx[m * KNN + s] = (int)(a[s] & 0xFFFFFFFFu);
}

// ===========================================================================
// MLP precompute (unchanged — passed R6/R8-R11)
// ===========================================================================

__global__ void const_kernel(const float* __restrict__ ew1, float* __restrict__ cst)
{
    int c = threadIdx.x;   // 64 threads
    float w0 = ew1[32 * 64 + c], w1 = ew1[33 * 64 + c], w2 = ew1[34 * 64 + c];
    float v[9] = { w0, w1, w2, w0*w0, w1*w1, w2*w2, w0*w1, w0*w2, w1*w2 };
#pragma unroll
    for (int k = 0; k < 9; ++k) {
#pragma unroll
        for (int off = 32; off; off >>= 1) v[k] += __shfl_xor(v[k], off);
    }
    if (c == 0) {
        cst[0] = v[0]; cst[1] = v[1]; cst[2] = v[2];
        cst[3] = v[3]; cst[4] = v[4]; cst[5] = v[5];
        cst[6] = v[6]; cst[7] = v[7]; cst[8] = v[8];
    }
}

__global__ __launch_bounds__(256) void pre_edge_kernel(
    const float* __restrict__ feats, const float* __restrict__ ew1,
    const float* __restrict__ eb1, float* __restrict__ pre,
    float* __restrict__ aux)
{
    int t = blockIdx.x * 256 + threadIdx.x;
    int n = t >> 6, c = t & 63;
    float acc = eb1[c];
#pragma unroll
    for (int i = 0; i < CIN; ++i)
        acc = fmaf(feats[n * CIN + i], ew1[i * COUT + c], acc);
    pre[t] = acc;

    float w0 = ew1[32 * 64 + c], w1 = ew1[33 * 64 + c], w2 = ew1[34 * 64 + c];
    float v[5] = { acc, acc * acc, acc * w0, acc * w1, acc * w2 };
#pragma unroll
    for (int k = 0; k < 5; ++k) {
#pragma unroll
        for (int off = 32; off; off >>= 1) v[k] += __shfl_xor(v[k], off);
    }
    if (c == 0) {
        aux[n * 8 + 0] = v[0]; aux[n * 8 + 1] = v[1];
        aux[n * 8 + 2] = v[2]; aux[n * 8 + 3] = v[3]; aux[n * 8 + 4] = v[4];
    }
}

// ===========================================================================
// Main MLP — same math as R6/R8-R11 (passed), j-loop software-pipelined:
// all 16 knn indices hoisted to SGPRs upfront; j+1's (aux,verts,pre) loads
// issued before j's compute to break the serial 3-hop latency chain.
// ===========================================================================
__device__ __forceinline__ float gelu_fast(float x) {
    float t = fmaf(0.044715f, x * x, 1.0f);
    float u = 0.7978845608028654f * x * t;
    float e = __expf(-2.0f * u);
    return x * __builtin_amdgcn_rcpf(1.0f + e);
}

__device__ __forceinline__ float lane_bcast(float v, int lane) {
    return __uint_as_float(__builtin_amdgcn_readlane(__float_as_uint(v), lane));
}

__global__ __launch_bounds__(MLP_BLOCK, 4) void mlp_kernel(
    const float* __restrict__ verts,
    const float* __restrict__ grid_verts,
    const float* __restrict__ grid_feat,
    const float* __restrict__ pre,
    const float* __restrict__ aux,
    const float* __restrict__ cst,
    const int*   __restrict__ knn_idx,
    const float* __restrict__ ew1,
    const float* __restrict__ eg1, const float* __restrict__ ebt1,
    const float* __restrict__ ew2, const float* __restrict__ eb2,
    const float* __restrict__ ow1, const float* __restrict__ ob1,
    const float* __restrict__ og1, const float* __restrict__ obt1,
    const float* __restrict__ ow2, const float* __restrict__ ob2,
    float* __restrict__ out)
{
    __shared__ float s_ew1r[3 * 64];
    __shared__ float s_ew2[64 * 64];
    __shared__ float s_ow1[160 * 64];
    __shared__ float s_ow2[64 * 64];
    __shared__ float s_eg1[64], s_ebt1[64], s_eb2[64];
    __shared__ float s_ob1[64], s_og1[64], s_obt1[64], s_ob2[64];

    const int tid = threadIdx.x;
    for (int t = tid; t < 3 * 64;  t += MLP_BLOCK) s_ew1r[t] = ew1[32 * 64 + t];
    for (int t = tid; t < 64 * 64; t += MLP_BLOCK) s_ew2[t]  = ew2[t];
    for (int t = tid; t < 160 * 64; t += MLP_BLOCK) s_ow1[t] = ow1[t];
    for (int t = tid; t < 64 * 64; t += MLP_BLOCK) s_ow2[t]  = ow2[t];
    if (tid < 64) {
        s_eg1[tid] = eg1[tid];  s_ebt1[tid] = ebt1[tid]; s_eb2[tid] = eb2[tid];
        s_ob1[tid] = ob1[tid];  s_og1[tid] = og1[tid];
        s_obt1[tid] = obt1[tid]; s_ob2[tid] = ob2[tid];
    }
    __syncthreads();

    const int lane = tid & 63;
    const int wave = tid >> 6;
    const int c    = lane;
    const int grp  = blockIdx.x * WPB + wave;
    const int m0   = __builtin_amdgcn_readfirstlane(grp * MT);

    const float Ws0 = cst[0], Ws1 = cst[1], Ws2 = cst[2];
    const float Gxx = cst[3], Gyy = cst[4], Gzz = cst[5];
    const float Gxy = cst[6], Gxz = cst[7], Gyz = cst[8];

    float gvx[MT], gvy[MT], gvz[MT];
#pragma unroll
    for (int p = 0; p < MT; ++p) {
        gvx[p] = grid_verts[(m0 + p) * 3 + 0];
        gvy[p] = grid_verts[(m0 + p) * 3 + 1];
        gvz[p] = grid_verts[(m0 + p) * 3 + 2];
    }

    float gsum[MT];
#pragma unroll
    for (int p = 0; p < MT; ++p) gsum[p] = 0.0f;

    const float inv64 = 1.0f / 64.0f;
    for (int p = 0; p < MT; ++p) {
        // hoist all 16 neighbor indices into SGPRs (2x s_load_dwordx8)
        int ns[KNN];
#pragma unroll
        for (int j = 0; j < KNN; ++j)
            ns[j] = __builtin_amdgcn_readfirstlane(knn_idx[(m0 + p) * KNN + j]);

        // prime pipeline with j=0 data
        int n = ns[0];
        float S1  = aux[n * 8 + 0], Q = aux[n * 8 + 1];
        float P1x = aux[n * 8 + 2], P1y = aux[n * 8 + 3], P1z = aux[n * 8 + 4];
        float vx = verts[n * 3 + 0], vy = verts[n * 3 + 1], vz = verts[n * 3 + 2];
        float pv = pre[(size_t)n * COUT + c];

#pragma unroll
        for (int j = 0; j < KNN; ++j) {
            // issue j+1's loads before j's compute
            int nn = ns[(j + 1 < KNN) ? j + 1 : j];
            float S1n  = aux[nn * 8 + 0], Qn = aux[nn * 8 + 1];
            float P1xn = aux[nn * 8 + 2], P1yn = aux[nn * 8 + 3], P1zn = aux[nn * 8 + 4];
            float vxn = verts[nn * 3 + 0], vyn = verts[nn * 3 + 1], vzn = verts[nn * 3 + 2];
            float pvn = pre[(size_t)nn * COUT + c];

            float rx = vx - gvx[p];
            float ry = vy - gvy[p];
            float rz = vz - gvz[p];
            float hv = pv;
            hv = fmaf(rx, s_ew1r[0 * 64 + c], hv);
            hv = fmaf(ry, s_ew1r[1 * 64 + c], hv);
            hv = fmaf(rz, s_ew1r[2 * 64 + c], hv);
            float s1 = S1 + rx * Ws0 + ry * Ws1 + rz * Ws2;
            float s2 = Q + 2.0f * (rx * P1x + ry * P1y + rz * P1z)
                     + rx * rx * Gxx + ry * ry * Gyy + rz * rz * Gzz
                     + 2.0f * (rx * ry * Gxy + rx * rz * Gxz + ry * rz * Gyz);
            float mean = s1 * inv64;
            float var  = s2 * inv64 - mean * mean;
            float xn = (hv - mean) * rsqrtf(var + 1e-5f);
            gsum[p] += gelu_fast(xn * s_eg1[c] + s_ebt1[c]);

            S1 = S1n; Q = Qn; P1x = P1xn; P1y = P1yn; P1z = P1zn;
            vx = vxn; vy = vyn; vz = vzn; pv = pvn;
        }
    }

    float A[MT];
#pragma unroll
    for (int p = 0; p < MT; ++p) { gsum[p] *= (1.0f / 16.0f); A[p] = s_eb2[c]; }
    for (int jj = 0; jj < 64; ++jj) {
        float w = s_ew2[jj * 64 + c];
#pragma unroll
        for (int p = 0; p < MT; ++p)
            A[p] = fmaf(lane_bcast(gsum[p], jj), w, A[p]);
    }

    float gfa[MT], gfb[MT];
#pragma unroll
    for (int p = 0; p < MT; ++p) {
        gfa[p] = grid_feat[(size_t)(m0 + p) * CPROV + c];
        gfb[p] = grid_feat[(size_t)(m0 + p) * CPROV + 64 + (c & 31)];
    }
    float t1[MT];
#pragma unroll
    for (int p = 0; p < MT; ++p) t1[p] = s_ob1[c];
    for (int jj = 0; jj < 64; ++jj) {
        float w = s_ow1[jj * 64 + c];
#pragma unroll
        for (int p = 0; p < MT; ++p)
            t1[p] = fmaf(lane_bcast(A[p], jj), w, t1[p]);
    }
    for (int i = 0; i < 64; ++i) {
        float w = s_ow1[(64 + i) * 64 + c];
#pragma unroll
        for (int p = 0; p < MT; ++p)
            t1[p] = fmaf(lane_bcast(gfa[p], i), w, t1[p]);
    }
    for (int i = 0; i < 32; ++i) {
        float w = s_ow1[(128 + i) * 64 + c];
#pragma unroll
        for (int p = 0; p < MT; ++p)
            t1[p] = fmaf(lane_bcast(gfb[p], i), w, t1[p]);
    }

#pragma unroll
    for (int p = 0; p < MT; ++p) {
        float x = t1[p];
        float s = x, s2 = x * x;
#pragma unroll
        for (int off = 32; off; off >>= 1) {
            s  += __shfl_xor(s, off);
            s2 += __shfl_xor(s2, off);
        }
        float mean = s * inv64;
        float var  = s2 * inv64 - mean * mean;
        float xn = (x - mean) * rsqrtf(var + 1e-5f);
        t1[p] = gelu_fast(xn * s_og1[c] + s_obt1[c]);
    }

    float o[MT];
#pragma unroll
    for (int p = 0; p < MT; ++p) o[p] = s_ob2[c];
    for (int jj = 0; jj < 64; ++jj) {
        float w = s_ow2[jj * 64 + c];
#pragma unroll
        for (int p = 0; p < MT; ++p)
            o[p] = fmaf(lane_bcast(t1[p], jj), w, o[p]);
    }
#pragma unroll
    for (int p = 0; p < MT; ++p)
        out[(size_t)(m0 + p) * COUT + c] = o[p];
}

// ---------------------------------------------------------------------------
extern "C" void kernel_launch(void* const* d_in, const int* in_sizes, int n_in,
                              void* d_out, int out_size, void* d_ws, size_t ws_size,
                              hipStream_t stream)
{
    const float* verts  = (const float*)d_in[0];
    const float* feats  = (const float*)d_in[1];
    const float* gverts = (const float*)d_in[2];
    const float* gfeat  = (const float*)d_in[3];
    const float* ew1    = (const float*)d_in[4];
    const float* eb1    = (const float*)d_in[5];
    const float* eg1    = (const float*)d_in[6];
    const float* ebt1   = (const float*)d_in[7];
    const float* ew2    = (const float*)d_in[8];
    const float* eb2    = (const float*)d_in[9];
    const float* ow1    = (const float*)d_in[10];
    const float* ob1    = (const float*)d_in[11];
    const float* og1    = (const float*)d_in[12];
    const float* obt1   = (const float*)d_in[13];
    const float* ow2    = (const float*)d_in[14];
    const float* ob2    = (const float*)d_in[15];
    float* out = (float*)d_out;

    char* ws = (char*)d_ws;
    int*    counts  = (int*)(ws + 0);              // 128 KB
    int*    prefix  = (int*)(ws + 131072);         // 32769 ints
    float*  tau     = (float*)(ws + 262152);       // 128 KB
    int*    knn_idx = (int*)(ws + 393224);         // 2 MB -> ends 2490376
    unsigned long long* cand = (unsigned long long*)(ws + 2490376);
    // pre/aux/cst overlay cand (dead after knn_merge)
    float*  pre     = (float*)(ws + 2490376);      // 2 MB
    float*  aux     = (float*)(ws + 4587528);      // 256 KB
    float*  cst     = (float*)(ws + 4849672);      // 64 B

    // 16 chunks when cand (NM*16*KNN*8 = 33.5 MB) fits in ws; else proven 4.
    const size_t need16 = 2490376 + (size_t)NM * 16 * KNN * 8;
    const int nch = (ws_size >= need16) ? 16 : 4;

    hipMemsetAsync(counts, 0, 32768 * sizeof(int), stream);
    bin_count_kernel<<<NV / 256, 256, 0, stream>>>(verts, counts);
    prefix_kernel<<<1, 1024, 0, stream>>>(counts, prefix);
    radius_kernel<<<NM / 256, 256, 0, stream>>>(gverts, prefix, tau);
    knn_partial_kernel<<<dim3(NM / 256, nch), 256, 0, stream>>>(verts, gverts, tau, cand);
    knn_merge_kernel<<<NM / 256, 256, 0, stream>>>(cand, knn_idx, nch);
    pre_edge_kernel<<<(NV * COUT) / 256, 256, 0, stream>>>(feats, ew1, eb1, pre, aux);
    const_kernel<<<1, 64, 0, stream>>>(ew1, cst);
    mlp_kernel<<<NM / (MT * WPB), MLP_BLOCK, 0, stream>>>(verts, gverts, gfeat,
        pre, aux, cst, knn_idx,
        ew1, eg1, ebt1, ew2, eb2, ow1, ob1, og1, obt1, ow2, ob2, out);
}

// Round 13
// 416.756 us; speedup vs baseline: 5.2260x; 5.2260x over previous
//
#include <hip/hip_runtime.h>
#include <cfloat>
#include <cstdint>

#define NV    8192
#define NM    32768
#define KNN   16
#define CIN   32
#define COUT  64
#define CPROV 96
#define SUB   256
#define CAP   8
#define MT    8      // grid points per wave in mlp kernel
#define MLP_BLOCK 1024
#define WPB   (MLP_BLOCK/64)

// ===========================================================================
// KNN: validated selection (full scan in index order, u64-key min-16,
// tau-seeded self-tightening d2-domain gate, LDS FIFO + branchless merge —
// R8-R12). nch runtime: 16 chunks when ws fits the 33.5MB cand buffer
// (2048 blocks -> residency LDS-limited at 8 blocks/CU), else proven 4.
// R13 fix: __launch_bounds__(256,2) as validated in R9 (44 VGPR, no spill).
// R12's (256,8) capped VGPRs at 64 -> a[16] u64 spilled to scratch ->
// 8.3 GB HBM traffic, 12x regression. Occupancy comes from the grid.
// Golden d2 path (validated R4/R6/R8-R12): q=grid*32, r=vert*32; qq/rr plain
// ascending mul/add; dot = fma(q2,r2, fma(q1,r1, q0*r0));
// d2 = fmaf(-2,dot,qq+rr)  (bit-identical to (qq+rr)-2*dot; 2*dot exact).
// ===========================================================================

__device__ __forceinline__ unsigned long long d2key(float d2, unsigned int idx) {
    unsigned int b = __float_as_uint(d2);
    b ^= (b & 0x80000000u) ? 0xFFFFFFFFu : 0x80000000u;  // total-order map
    return ((unsigned long long)b << 32) | idx;
}

__device__ __forceinline__ float key_d2f(unsigned long long key) {
    unsigned int b = (unsigned int)(key >> 32);
    b = (b & 0x80000000u) ? (b ^ 0x80000000u) : ~b;      // inverse map
    return __uint_as_float(b);
}

__device__ __forceinline__ void key_insert(unsigned long long* a,
                                           unsigned long long key) {
    // branchless sorted (ascending) insert-and-drop-max
#pragma unroll
    for (int i = KNN - 1; i >= 1; --i) {
        unsigned long long hi = (a[i-1] > key) ? a[i-1] : key;
        a[i] = (hi < a[i]) ? hi : a[i];
    }
    a[0] = (key < a[0]) ? key : a[0];
}

__device__ __forceinline__ int bin_of(float x) {
    int b = (int)(x * 32.0f);
    return min(31, max(0, b));
}

__global__ __launch_bounds__(256) void bin_count_kernel(
    const float* __restrict__ verts, int* __restrict__ counts)
{
    int v = blockIdx.x * 256 + threadIdx.x;
    int bx = bin_of(verts[v * 3 + 0]);
    int by = bin_of(verts[v * 3 + 1]);
    int bz = bin_of(verts[v * 3 + 2]);
    atomicAdd(&counts[(bx * 32 + by) * 32 + bz], 1);
}

__global__ __launch_bounds__(1024) void prefix_kernel(
    const int* __restrict__ counts, int* __restrict__ prefix)
{
    __shared__ int lds[1024];
    int tid = threadIdx.x;
    int local[32]; int s = 0;
#pragma unroll
    for (int i = 0; i < 32; ++i) { local[i] = counts[tid * 32 + i]; s += local[i]; }
    lds[tid] = s; __syncthreads();
    for (int off = 1; off < 1024; off <<= 1) {
        int v = (tid >= off) ? lds[tid - off] : 0;
        __syncthreads();
        lds[tid] += v;
        __syncthreads();
    }
    int run = lds[tid] - s;
#pragma unroll
    for (int i = 0; i < 32; ++i) { prefix[tid * 32 + i] = run; run += local[i]; }
    if (tid == 1023) prefix[32768] = run;
}

// tau[m] = 3*(R+1)^2 where radius-R cell cube holds >= 16 points (validated)
__global__ __launch_bounds__(256) void radius_kernel(
    const float* __restrict__ grid_verts, const int* __restrict__ prefix,
    float* __restrict__ tau)
{
    int m = blockIdx.x * 256 + threadIdx.x;
    int bx = bin_of(grid_verts[m * 3 + 0]);
    int by = bin_of(grid_verts[m * 3 + 1]);
    int bz = bin_of(grid_verts[m * 3 + 2]);
    int R = 1;
    for (; R < 32; ++R) {
        int cnt = 0;
        int xlo = max(0, bx - R), xhi = min(31, bx + R);
        int ylo = max(0, by - R), yhi = min(31, by + R);
        int zlo = max(0, bz - R), zhi = min(31, bz + R);
        for (int x = xlo; x <= xhi; ++x)
            for (int y = ylo; y <= yhi; ++y) {
                int c = (x * 32 + y) * 32;
                cnt += prefix[c + zhi + 1] - prefix[c + zlo];
            }
        if (cnt >= KNN) break;
    }
    float Rp = (float)(R + 1);
    tau[m] = 3.0f * Rp * Rp;
}

__global__ __launch_bounds__(256, 2) void knn_partial_kernel(
    const float* __restrict__ verts,
    const float* __restrict__ grid_verts,
    const float* __restrict__ tau,
    unsigned long long* __restrict__ cand)   // (NM, nch*KNN)
{
    __shared__ float4 sv[SUB];                       // 4 KB
    __shared__ unsigned long long sbuf[CAP][256];    // 16 KB
    const int tid   = threadIdx.x;
    const int m     = blockIdx.x * 256 + tid;
    const int chunk = blockIdx.y;
    const int nch   = gridDim.y;
    const int chunklen = NV / nch;
    const int nsub  = chunklen / SUB;

    const float q0 = __fmul_rn(grid_verts[m * 3 + 0], 32.0f);
    const float q1 = __fmul_rn(grid_verts[m * 3 + 1], 32.0f);
    const float q2 = __fmul_rn(grid_verts[m * 3 + 2], 32.0f);
    const float qq = __fadd_rn(__fadd_rn(__fmul_rn(q0, q0), __fmul_rn(q1, q1)),
                               __fmul_rn(q2, q2));

    // seed = key(bound), idx 0; bound > all golden top-16 d2 (validated margin)
    const float bound = tau[m] + 0.13f;
    unsigned int bb = __float_as_uint(bound) ^ 0x80000000u;  // bound > 0
    const unsigned long long seed = ((unsigned long long)bb << 32);

    unsigned long long a[KNN];
#pragma unroll
    for (int s = 0; s < KNN; ++s) a[s] = seed;
    float gd = bound;      // d2-domain gate = d2 part of a[15]
    int cnt = 0;

    for (int sub = 0; sub < nsub; ++sub) {
        __syncthreads();
        {
            int v = chunk * chunklen + sub * SUB + tid;
            float r0 = __fmul_rn(verts[v * 3 + 0], 32.0f);
            float r1 = __fmul_rn(verts[v * 3 + 1], 32.0f);
            float r2 = __fmul_rn(verts[v * 3 + 2], 32.0f);
            float rr = __fadd_rn(__fadd_rn(__fmul_rn(r0, r0), __fmul_rn(r1, r1)),
                                 __fmul_rn(r2, r2));
            sv[tid] = make_float4(r0, r1, r2, rr);
        }
        __syncthreads();

        const unsigned int base = chunk * chunklen + sub * SUB;
        for (int t = 0; t < SUB; t += 8) {
            float d2v[8];
#pragma unroll
            for (int k = 0; k < 8; ++k) {
                float4 v = sv[t + k];
                float dot = fmaf(q2, v.z, fmaf(q1, v.y, __fmul_rn(q0, v.x)));
                d2v[k] = fmaf(-2.0f, dot, __fadd_rn(qq, v.w));
            }
#pragma unroll
            for (int k = 0; k < 8; ++k) {
                if (d2v[k] <= gd) {   // conservative gate; exact insert decides
                    unsigned long long key = d2key(d2v[k], base + t + k);
                    if (cnt < CAP) { sbuf[cnt][tid] = key; ++cnt; }
                    else {  // overflow: exact direct insert, tighten gate
                        key_insert(a, key);
                        gd = key_d2f(a[KNN - 1]);
                    }
                }
            }
        }
        // merge private FIFO (lane-private; no barrier needed)
        int mx = cnt;
#pragma unroll
        for (int off = 32; off; off >>= 1) mx = max(mx, __shfl_xor(mx, off));
        for (int k = 0; k < mx; ++k) {
            unsigned long long key = (k < cnt) ? sbuf[k][tid] : ~0ULL;
            key_insert(a, key);
        }
        if (mx) gd = key_d2f(a[KNN - 1]);
        cnt = 0;
    }

    unsigned long long* o = cand + (size_t)m * (nch * KNN) + chunk * KNN;
#pragma unroll
    for (int s = 0; s < KNN; ++s) o[s] = a[s];
}

__global__ __launch_bounds__(256) void knn_merge_kernel(
    const unsigned long long* __restrict__ cand, int* __restrict__ knn_idx,
    int nch)
{
    const int m = blockIdx.x * 256 + threadIdx.x;
    unsigned long long a[KNN];
#pragma unroll
    for (int s = 0; s < KNN; ++s) a[s] = ~0ULL;
    const int nk = nch * KNN;
    for (int k = 0; k < nk; ++k) {
        unsigned long long key = cand[(size_t)m * nk + k];
        if (key < a[KNN - 1]) key_insert(a, key);
    }
#pragma unroll
    for (int s = 0; s < KNN; ++s)
        knn_idx[m * KNN + s] = (int)(a[s] & 0xFFFFFFFFu);
}

// ===========================================================================
// MLP precompute (unchanged — passed R6/R8-R12)
// ===========================================================================

__global__ void const_kernel(const float* __restrict__ ew1, float* __restrict__ cst)
{
    int c = threadIdx.x;   // 64 threads
    float w0 = ew1[32 * 64 + c], w1 = ew1[33 * 64 + c], w2 = ew1[34 * 64 + c];
    float v[9] = { w0, w1, w2, w0*w0, w1*w1, w2*w2, w0*w1, w0*w2, w1*w2 };
#pragma unroll
    for (int k = 0; k < 9; ++k) {
#pragma unroll
        for (int off = 32; off; off >>= 1) v[k] += __shfl_xor(v[k], off);
    }
    if (c == 0) {
        cst[0] = v[0]; cst[1] = v[1]; cst[2] = v[2];
        cst[3] = v[3]; cst[4] = v[4]; cst[5] = v[5];
        cst[6] = v[6]; cst[7] = v[7]; cst[8] = v[8];
    }
}

__global__ __launch_bounds__(256) void pre_edge_kernel(
    const float* __restrict__ feats, const float* __restrict__ ew1,
    const float* __restrict__ eb1, float* __restrict__ pre,
    float* __restrict__ aux)
{
    int t = blockIdx.x * 256 + threadIdx.x;
    int n = t >> 6, c = t & 63;
    float acc = eb1[c];
#pragma unroll
    for (int i = 0; i < CIN; ++i)
        acc = fmaf(feats[n * CIN + i], ew1[i * COUT + c], acc);
    pre[t] = acc;

    float w0 = ew1[32 * 64 + c], w1 = ew1[33 * 64 + c], w2 = ew1[34 * 64 + c];
    float v[5] = { acc, acc * acc, acc * w0, acc * w1, acc * w2 };
#pragma unroll
    for (int k = 0; k < 5; ++k) {
#pragma unroll
        for (int off = 32; off; off >>= 1) v[k] += __shfl_xor(v[k], off);
    }
    if (c == 0) {
        aux[n * 8 + 0] = v[0]; aux[n * 8 + 1] = v[1];
        aux[n * 8 + 2] = v[2]; aux[n * 8 + 3] = v[3]; aux[n * 8 + 4] = v[4];
    }
}

// ===========================================================================
// Main MLP — same math as R6/R8-R12 (passed), j-loop software-pipelined
// (kept from R12: rest-of-pipeline time 260 -> ~225 us).
// ===========================================================================
__device__ __forceinline__ float gelu_fast(float x) {
    float t = fmaf(0.044715f, x * x, 1.0f);
    float u = 0.7978845608028654f * x * t;
    float e = __expf(-2.0f * u);
    return x * __builtin_amdgcn_rcpf(1.0f + e);
}

__device__ __forceinline__ float lane_bcast(float v, int lane) {
    return __uint_as_float(__builtin_amdgcn_readlane(__float_as_uint(v), lane));
}

__global__ __launch_bounds__(MLP_BLOCK, 4) void mlp_kernel(
    const float* __restrict__ verts,
    const float* __restrict__ grid_verts,
    const float* __restrict__ grid_feat,
    const float* __restrict__ pre,
    const float* __restrict__ aux,
    const float* __restrict__ cst,
    const int*   __restrict__ knn_idx,
    const float* __restrict__ ew1,
    const float* __restrict__ eg1, const float* __restrict__ ebt1,
    const float* __restrict__ ew2, const float* __restrict__ eb2,
    const float* __restrict__ ow1, const float* __restrict__ ob1,
    const float* __restrict__ og1, const float* __restrict__ obt1,
    const float* __restrict__ ow2, const float* __restrict__ ob2,
    float* __restrict__ out)
{
    __shared__ float s_ew1r[3 * 64];
    __shared__ float s_ew2[64 * 64];
    __shared__ float s_ow1[160 * 64];
    __shared__ float s_ow2[64 * 64];
    __shared__ float s_eg1[64], s_ebt1[64], s_eb2[64];
    __shared__ float s_ob1[64], s_og1[64], s_obt1[64], s_ob2[64];

    const int tid = threadIdx.x;
    for (int t = tid; t < 3 * 64;  t += MLP_BLOCK) s_ew1r[t] = ew1[32 * 64 + t];
    for (int t = tid; t < 64 * 64; t += MLP_BLOCK) s_ew2[t]  = ew2[t];
    for (int t = tid; t < 160 * 64; t += MLP_BLOCK) s_ow1[t] = ow1[t];
    for (int t = tid; t < 64 * 64; t += MLP_BLOCK) s_ow2[t]  = ow2[t];
    if (tid < 64) {
        s_eg1[tid] = eg1[tid];  s_ebt1[tid] = ebt1[tid]; s_eb2[tid] = eb2[tid];
        s_ob1[tid] = ob1[tid];  s_og1[tid] = og1[tid];
        s_obt1[tid] = obt1[tid]; s_ob2[tid] = ob2[tid];
    }
    __syncthreads();

    const int lane = tid & 63;
    const int wave = tid >> 6;
    const int c    = lane;
    const int grp  = blockIdx.x * WPB + wave;
    const int m0   = __builtin_amdgcn_readfirstlane(grp * MT);

    const float Ws0 = cst[0], Ws1 = cst[1], Ws2 = cst[2];
    const float Gxx = cst[3], Gyy = cst[4], Gzz = cst[5];
    const float Gxy = cst[6], Gxz = cst[7], Gyz = cst[8];

    float gvx[MT], gvy[MT], gvz[MT];
#pragma unroll
    for (int p = 0; p < MT; ++p) {
        gvx[p] = grid_verts[(m0 + p) * 3 + 0];
        gvy[p] = grid_verts[(m0 + p) * 3 + 1];
        gvz[p] = grid_verts[(m0 + p) * 3 + 2];
    }

    float gsum[MT];
#pragma unroll
    for (int p = 0; p < MT; ++p) gsum[p] = 0.0f;

    const float inv64 = 1.0f / 64.0f;
    for (int p = 0; p < MT; ++p) {
        // hoist all 16 neighbor indices into SGPRs (2x s_load_dwordx8)
        int ns[KNN];
#pragma unroll
        for (int j = 0; j < KNN; ++j)
            ns[j] = __builtin_amdgcn_readfirstlane(knn_idx[(m0 + p) * KNN + j]);

        // prime pipeline with j=0 data
        int n = ns[0];
        float S1  = aux[n * 8 + 0], Q = aux[n * 8 + 1];
        float P1x = aux[n * 8 + 2], P1y = aux[n * 8 + 3], P1z = aux[n * 8 + 4];
        float vx = verts[n * 3 + 0], vy = verts[n * 3 + 1], vz = verts[n * 3 + 2];
        float pv = pre[(size_t)n * COUT + c];

#pragma unroll
        for (int j = 0; j < KNN; ++j) {
            // issue j+1's loads before j's compute
            int nn = ns[(j + 1 < KNN) ? j + 1 : j];
            float S1n  = aux[nn * 8 + 0], Qn = aux[nn * 8 + 1];
            float P1xn = aux[nn * 8 + 2], P1yn = aux[nn * 8 + 3], P1zn = aux[nn * 8 + 4];
            float vxn = verts[nn * 3 + 0], vyn = verts[nn * 3 + 1], vzn = verts[nn * 3 + 2];
            float pvn = pre[(size_t)nn * COUT + c];

            float rx = vx - gvx[p];
            float ry = vy - gvy[p];
            float rz = vz - gvz[p];
            float hv = pv;
            hv = fmaf(rx, s_ew1r[0 * 64 + c], hv);
            hv = fmaf(ry, s_ew1r[1 * 64 + c], hv);
            hv = fmaf(rz, s_ew1r[2 * 64 + c], hv);
            float s1 = S1 + rx * Ws0 + ry * Ws1 + rz * Ws2;
            float s2 = Q + 2.0f * (rx * P1x + ry * P1y + rz * P1z)
                     + rx * rx * Gxx + ry * ry * Gyy + rz * rz * Gzz
                     + 2.0f * (rx * ry * Gxy + rx * rz * Gxz + ry * rz * Gyz);
            float mean = s1 * inv64;
            float var  = s2 * inv64 - mean * mean;
            float xn = (hv - mean) * rsqrtf(var + 1e-5f);
            gsum[p] += gelu_fast(xn * s_eg1[c] + s_ebt1[c]);

            S1 = S1n; Q = Qn; P1x = P1xn; P1y = P1yn; P1z = P1zn;
            vx = vxn; vy = vyn; vz = vzn; pv = pvn;
        }
    }

    float A[MT];
#pragma unroll
    for (int p = 0; p < MT; ++p) { gsum[p] *= (1.0f / 16.0f); A[p] = s_eb2[c]; }
    for (int jj = 0; jj < 64; ++jj) {
        float w = s_ew2[jj * 64 + c];
#pragma unroll
        for (int p = 0; p < MT; ++p)
            A[p] = fmaf(lane_bcast(gsum[p], jj), w, A[p]);
    }

    float gfa[MT], gfb[MT];
#pragma unroll
    for (int p = 0; p < MT; ++p) {
        gfa[p] = grid_feat[(size_t)(m0 + p) * CPROV + c];
        gfb[p] = grid_feat[(size_t)(m0 + p) * CPROV + 64 + (c & 31)];
    }
    float t1[MT];
#pragma unroll
    for (int p = 0; p < MT; ++p) t1[p] = s_ob1[c];
    for (int jj = 0; jj < 64; ++jj) {
        float w = s_ow1[jj * 64 + c];
#pragma unroll
        for (int p = 0; p < MT; ++p)
            t1[p] = fmaf(lane_bcast(A[p], jj), w, t1[p]);
    }
    for (int i = 0; i < 64; ++i) {
        float w = s_ow1[(64 + i) * 64 + c];
#pragma unroll
        for (int p = 0; p < MT; ++p)
            t1[p] = fmaf(lane_bcast(gfa[p], i), w, t1[p]);
    }
    for (int i = 0; i < 32; ++i) {
        float w = s_ow1[(128 + i) * 64 + c];
#pragma unroll
        for (int p = 0; p < MT; ++p)
            t1[p] = fmaf(lane_bcast(gfb[p], i), w, t1[p]);
    }

#pragma unroll
    for (int p = 0; p < MT; ++p) {
        float x = t1[p];
        float s = x, s2 = x * x;
#pragma unroll
        for (int off = 32; off; off >>= 1) {
            s  += __shfl_xor(s, off);
            s2 += __shfl_xor(s2, off);
        }
        float mean = s * inv64;
        float var  = s2 * inv64 - mean * mean;
        float xn = (x - mean) * rsqrtf(var + 1e-5f);
        t1[p] = gelu_fast(xn * s_og1[c] + s_obt1[c]);
    }

    float o[MT];
#pragma unroll
    for (int p = 0; p < MT; ++p) o[p] = s_ob2[c];
    for (int jj = 0; jj < 64; ++jj) {
        float w = s_ow2[jj * 64 + c];
#pragma unroll
        for (int p = 0; p < MT; ++p)
            o[p] = fmaf(lane_bcast(t1[p], jj), w, o[p]);
    }
#pragma unroll
    for (int p = 0; p < MT; ++p)
        out[(size_t)(m0 + p) * COUT + c] = o[p];
}

// ---------------------------------------------------------------------------
extern "C" void kernel_launch(void* const* d_in, const int* in_sizes, int n_in,
                              void* d_out, int out_size, void* d_ws, size_t ws_size,
                              hipStream_t stream)
{
    const float* verts  = (const float*)d_in[0];
    const float* feats  = (const float*)d_in[1];
    const float* gverts = (const float*)d_in[2];
    const float* gfeat  = (const float*)d_in[3];
    const float* ew1    = (const float*)d_in[4];
    const float* eb1    = (const float*)d_in[5];
    const float* eg1    = (const float*)d_in[6];
    const float* ebt1   = (const float*)d_in[7];
    const float* ew2    = (const float*)d_in[8];
    const float* eb2    = (const float*)d_in[9];
    const float* ow1    = (const float*)d_in[10];
    const float* ob1    = (const float*)d_in[11];
    const float* og1    = (const float*)d_in[12];
    const float* obt1   = (const float*)d_in[13];
    const float* ow2    = (const float*)d_in[14];
    const float* ob2    = (const float*)d_in[15];
    float* out = (float*)d_out;

    char* ws = (char*)d_ws;
    int*    counts  = (int*)(ws + 0);              // 128 KB
    int*    prefix  = (int*)(ws + 131072);         // 32769 ints
    float*  tau     = (float*)(ws + 262152);       // 128 KB
    int*    knn_idx = (int*)(ws + 393224);         // 2 MB -> ends 2490376
    unsigned long long* cand = (unsigned long long*)(ws + 2490376);
    // pre/aux/cst overlay cand (dead after knn_merge)
    float*  pre     = (float*)(ws + 2490376);      // 2 MB
    float*  aux     = (float*)(ws + 4587528);      // 256 KB
    float*  cst     = (float*)(ws + 4849672);      // 64 B

    // 16 chunks when cand (NM*16*KNN*8 = 33.5 MB) fits in ws; else proven 4.
    const size_t need16 = 2490376 + (size_t)NM * 16 * KNN * 8;
    const int nch = (ws_size >= need16) ? 16 : 4;

    hipMemsetAsync(counts, 0, 32768 * sizeof(int), stream);
    bin_count_kernel<<<NV / 256, 256, 0, stream>>>(verts, counts);
    prefix_kernel<<<1, 1024, 0, stream>>>(counts, prefix);
    radius_kernel<<<NM / 256, 256, 0, stream>>>(gverts, prefix, tau);
    knn_partial_kernel<<<dim3(NM / 256, nch), 256, 0, stream>>>(verts, gverts, tau, cand);
    knn_merge_kernel<<<NM / 256, 256, 0, stream>>>(cand, knn_idx, nch);
    pre_edge_kernel<<<(NV * COUT) / 256, 256, 0, stream>>>(feats, ew1, eb1, pre, aux);
    const_kernel<<<1, 64, 0, stream>>>(ew1, cst);
    mlp_kernel<<<NM / (MT * WPB), MLP_BLOCK, 0, stream>>>(verts, gverts, gfeat,
        pre, aux, cst, knn_idx,
        ew1, eg1, ebt1, ew2, eb2, ow1, ob1, og1, obt1, ow2, ob2, out);
}

// Round 14
// 403.779 us; speedup vs baseline: 5.3939x; 1.0321x over previous
//
#include <hip/hip_runtime.h>
#include <cfloat>
#include <cstdint>

#define NV    8192
#define NM    32768
#define KNN   16
#define CIN   32
#define COUT  64
#define CPROV 96
#define SUB   256
#define CAP   8
#define MT    8      // grid points per wave in mlp kernel
#define MLP_BLOCK 1024
#define WPB   (MLP_BLOCK/64)

// ===========================================================================
// KNN: validated selection (full scan in index order, u64-key min-16,
// tau-seeded self-tightening d2-domain gate, LDS FIFO + branchless merge —
// R8-R13). nch runtime: 16 chunks when ws fits the 33.5MB cand buffer.
// R14: cand layout transposed to [k][m] so knn_merge reads coalesce
// (was 2KB-stride gather). Write side stays coalesced (consecutive tid = m).
// Insertion order unchanged -> identical final min-16 set.
// knn_partial: __launch_bounds__(256,2) — R12's (256,8) spilled a[16] to
// scratch (8.3GB HBM, 12x regression). Occupancy comes from the grid.
// Golden d2 path (validated R4/R6/R8-R13): q=grid*32, r=vert*32; qq/rr plain
// ascending mul/add; dot = fma(q2,r2, fma(q1,r1, q0*r0));
// d2 = fmaf(-2,dot,qq+rr)  (bit-identical to (qq+rr)-2*dot; 2*dot exact).
// ===========================================================================

__device__ __forceinline__ unsigned long long d2key(float d2, unsigned int idx) {
    unsigned int b = __float_as_uint(d2);
    b ^= (b & 0x80000000u) ? 0xFFFFFFFFu : 0x80000000u;  // total-order map
    return ((unsigned long long)b << 32) | idx;
}

__device__ __forceinline__ float key_d2f(unsigned long long key) {
    unsigned int b = (unsigned int)(key >> 32);
    b = (b & 0x80000000u) ? (b ^ 0x80000000u) : ~b;      // inverse map
    return __uint_as_float(b);
}

__device__ __forceinline__ void key_insert(unsigned long long* a,
                                           unsigned long long key) {
    // branchless sorted (ascending) insert-and-drop-max
#pragma unroll
    for (int i = KNN - 1; i >= 1; --i) {
        unsigned long long hi = (a[i-1] > key) ? a[i-1] : key;
        a[i] = (hi < a[i]) ? hi : a[i];
    }
    a[0] = (key < a[0]) ? key : a[0];
}

__device__ __forceinline__ int bin_of(float x) {
    int b = (int)(x * 32.0f);
    return min(31, max(0, b));
}

__global__ __launch_bounds__(256) void bin_count_kernel(
    const float* __restrict__ verts, int* __restrict__ counts)
{
    int v = blockIdx.x * 256 + threadIdx.x;
    int bx = bin_of(verts[v * 3 + 0]);
    int by = bin_of(verts[v * 3 + 1]);
    int bz = bin_of(verts[v * 3 + 2]);
    atomicAdd(&counts[(bx * 32 + by) * 32 + bz], 1);
}

__global__ __launch_bounds__(1024) void prefix_kernel(
    const int* __restrict__ counts, int* __restrict__ prefix)
{
    __shared__ int lds[1024];
    int tid = threadIdx.x;
    int local[32]; int s = 0;
#pragma unroll
    for (int i = 0; i < 32; ++i) { local[i] = counts[tid * 32 + i]; s += local[i]; }
    lds[tid] = s; __syncthreads();
    for (int off = 1; off < 1024; off <<= 1) {
        int v = (tid >= off) ? lds[tid - off] : 0;
        __syncthreads();
        lds[tid] += v;
        __syncthreads();
    }
    int run = lds[tid] - s;
#pragma unroll
    for (int i = 0; i < 32; ++i) { prefix[tid * 32 + i] = run; run += local[i]; }
    if (tid == 1023) prefix[32768] = run;
}

// tau[m] = 3*(R+1)^2 where radius-R cell cube holds >= 16 points (validated)
__global__ __launch_bounds__(256) void radius_kernel(
    const float* __restrict__ grid_verts, const int* __restrict__ prefix,
    float* __restrict__ tau)
{
    int m = blockIdx.x * 256 + threadIdx.x;
    int bx = bin_of(grid_verts[m * 3 + 0]);
    int by = bin_of(grid_verts[m * 3 + 1]);
    int bz = bin_of(grid_verts[m * 3 + 2]);
    int R = 1;
    for (; R < 32; ++R) {
        int cnt = 0;
        int xlo = max(0, bx - R), xhi = min(31, bx + R);
        int ylo = max(0, by - R), yhi = min(31, by + R);
        int zlo = max(0, bz - R), zhi = min(31, bz + R);
        for (int x = xlo; x <= xhi; ++x)
            for (int y = ylo; y <= yhi; ++y) {
                int c = (x * 32 + y) * 32;
                cnt += prefix[c + zhi + 1] - prefix[c + zlo];
            }
        if (cnt >= KNN) break;
    }
    float Rp = (float)(R + 1);
    tau[m] = 3.0f * Rp * Rp;
}

__global__ __launch_bounds__(256, 2) void knn_partial_kernel(
    const float* __restrict__ verts,
    const float* __restrict__ grid_verts,
    const float* __restrict__ tau,
    unsigned long long* __restrict__ cand)   // (nch*KNN, NM) transposed
{
    __shared__ float4 sv[SUB];                       // 4 KB
    __shared__ unsigned long long sbuf[CAP][256];    // 16 KB
    const int tid   = threadIdx.x;
    const int m     = blockIdx.x * 256 + tid;
    const int chunk = blockIdx.y;
    const int nch   = gridDim.y;
    const int chunklen = NV / nch;
    const int nsub  = chunklen / SUB;

    const float q0 = __fmul_rn(grid_verts[m * 3 + 0], 32.0f);
    const float q1 = __fmul_rn(grid_verts[m * 3 + 1], 32.0f);
    const float q2 = __fmul_rn(grid_verts[m * 3 + 2], 32.0f);
    const float qq = __fadd_rn(__fadd_rn(__fmul_rn(q0, q0), __fmul_rn(q1, q1)),
                               __fmul_rn(q2, q2));

    // seed = key(bound), idx 0; bound > all golden top-16 d2 (validated margin)
    const float bound = tau[m] + 0.13f;
    unsigned int bb = __float_as_uint(bound) ^ 0x80000000u;  // bound > 0
    const unsigned long long seed = ((unsigned long long)bb << 32);

    unsigned long long a[KNN];
#pragma unroll
    for (int s = 0; s < KNN; ++s) a[s] = seed;
    float gd = bound;      // d2-domain gate = d2 part of a[15]
    int cnt = 0;

    for (int sub = 0; sub < nsub; ++sub) {
        __syncthreads();
        {
            int v = chunk * chunklen + sub * SUB + tid;
            float r0 = __fmul_rn(verts[v * 3 + 0], 32.0f);
            float r1 = __fmul_rn(verts[v * 3 + 1], 32.0f);
            float r2 = __fmul_rn(verts[v * 3 + 2], 32.0f);
            float rr = __fadd_rn(__fadd_rn(__fmul_rn(r0, r0), __fmul_rn(r1, r1)),
                                 __fmul_rn(r2, r2));
            sv[tid] = make_float4(r0, r1, r2, rr);
        }
        __syncthreads();

        const unsigned int base = chunk * chunklen + sub * SUB;
        for (int t = 0; t < SUB; t += 8) {
            float d2v[8];
#pragma unroll
            for (int k = 0; k < 8; ++k) {
                float4 v = sv[t + k];
                float dot = fmaf(q2, v.z, fmaf(q1, v.y, __fmul_rn(q0, v.x)));
                d2v[k] = fmaf(-2.0f, dot, __fadd_rn(qq, v.w));
            }
#pragma unroll
            for (int k = 0; k < 8; ++k) {
                if (d2v[k] <= gd) {   // conservative gate; exact insert decides
                    unsigned long long key = d2key(d2v[k], base + t + k);
                    if (cnt < CAP) { sbuf[cnt][tid] = key; ++cnt; }
                    else {  // overflow: exact direct insert, tighten gate
                        key_insert(a, key);
                        gd = key_d2f(a[KNN - 1]);
                    }
                }
            }
        }
        // merge private FIFO (lane-private; no barrier needed)
        int mx = cnt;
#pragma unroll
        for (int off = 32; off; off >>= 1) mx = max(mx, __shfl_xor(mx, off));
        for (int k = 0; k < mx; ++k) {
            unsigned long long key = (k < cnt) ? sbuf[k][tid] : ~0ULL;
            key_insert(a, key);
        }
        if (mx) gd = key_d2f(a[KNN - 1]);
        cnt = 0;
    }

    // transposed write: cand[(chunk*KNN+s)*NM + m] — coalesced in m per s
#pragma unroll
    for (int s = 0; s < KNN; ++s)
        cand[(size_t)(chunk * KNN + s) * NM + m] = a[s];
}

__global__ __launch_bounds__(256) void knn_merge_kernel(
    const unsigned long long* __restrict__ cand, int* __restrict__ knn_idx,
    int nch)
{
    const int m = blockIdx.x * 256 + threadIdx.x;
    unsigned long long a[KNN];
#pragma unroll
    for (int s = 0; s < KNN; ++s) a[s] = ~0ULL;
    const int nk = nch * KNN;
    for (int k = 0; k < nk; ++k) {
        unsigned long long key = cand[(size_t)k * NM + m];   // coalesced
        if (key < a[KNN - 1]) key_insert(a, key);
    }
#pragma unroll
    for (int s = 0; s < KNN; ++s)
        knn_idx[m * KNN + s] = (int)(a[s] & 0xFFFFFFFFu);
}

// ===========================================================================
// MLP precompute (unchanged — passed R6/R8-R13)
// ===========================================================================

__global__ void const_kernel(const float* __restrict__ ew1, float* __restrict__ cst)
{
    int c = threadIdx.x;   // 64 threads
    float w0 = ew1[32 * 64 + c], w1 = ew1[33 * 64 + c], w2 = ew1[34 * 64 + c];
    float v[9] = { w0, w1, w2, w0*w0, w1*w1, w2*w2, w0*w1, w0*w2, w1*w2 };
#pragma unroll
    for (int k = 0; k < 9; ++k) {
#pragma unroll
        for (int off = 32; off; off >>= 1) v[k] += __shfl_xor(v[k], off);
    }
    if (c == 0) {
        cst[0] = v[0]; cst[1] = v[1]; cst[2] = v[2];
        cst[3] = v[3]; cst[4] = v[4]; cst[5] = v[5];
        cst[6] = v[6]; cst[7] = v[7]; cst[8] = v[8];
    }
}

__global__ __launch_bounds__(256) void pre_edge_kernel(
    const float* __restrict__ feats, const float* __restrict__ ew1,
    const float* __restrict__ eb1, float* __restrict__ pre,
    float* __restrict__ aux)
{
    int t = blockIdx.x * 256 + threadIdx.x;
    int n = t >> 6, c = t & 63;
    float acc = eb1[c];
#pragma unroll
    for (int i = 0; i < CIN; ++i)
        acc = fmaf(feats[n * CIN + i], ew1[i * COUT + c], acc);
    pre[t] = acc;

    float w0 = ew1[32 * 64 + c], w1 = ew1[33 * 64 + c], w2 = ew1[34 * 64 + c];
    float v[5] = { acc, acc * acc, acc * w0, acc * w1, acc * w2 };
#pragma unroll
    for (int k = 0; k < 5; ++k) {
#pragma unroll
        for (int off = 32; off; off >>= 1) v[k] += __shfl_xor(v[k], off);
    }
    if (c == 0) {
        aux[n * 8 + 0] = v[0]; aux[n * 8 + 1] = v[1];
        aux[n * 8 + 2] = v[2]; aux[n * 8 + 3] = v[3]; aux[n * 8 + 4] = v[4];
    }
}

// ===========================================================================
// Main MLP — R14 restructure (output BIT-IDENTICAL to R13's):
// Phase 1: the 128 (p,j) pairs' LN stats (rx,ry,rz,mean,istd) — previously
// recomputed redundantly by all 64 channel-lanes (~30 VALU ops/iter) — are
// computed ONCE per pair, one pair per lane (2 rounds), parked in per-wave
// LDS. Phase 2: channel loop is just pre + 3 fma + (hv-mean)*istd + gelu.
// No manual prefetch pipeline (R13's was defeated: VGPR_Count=32 -> compiler
// pushed arrays to AGPRs, ~3.5x VALU inflation). Plain launch bounds.
// ===========================================================================
__device__ __forceinline__ float gelu_fast(float x) {
    float t = fmaf(0.044715f, x * x, 1.0f);
    float u = 0.7978845608028654f * x * t;
    float e = __expf(-2.0f * u);
    return x * __builtin_amdgcn_rcpf(1.0f + e);
}

__device__ __forceinline__ float lane_bcast(float v, int lane) {
    return __uint_as_float(__builtin_amdgcn_readlane(__float_as_uint(v), lane));
}

__global__ __launch_bounds__(MLP_BLOCK) void mlp_kernel(
    const float* __restrict__ verts,
    const float* __restrict__ grid_verts,
    const float* __restrict__ grid_feat,
    const float* __restrict__ pre,
    const float* __restrict__ aux,
    const float* __restrict__ cst,
    const int*   __restrict__ knn_idx,
    const float* __restrict__ ew1,
    const float* __restrict__ eg1, const float* __restrict__ ebt1,
    const float* __restrict__ ew2, const float* __restrict__ eb2,
    const float* __restrict__ ow1, const float* __restrict__ ob1,
    const float* __restrict__ og1, const float* __restrict__ obt1,
    const float* __restrict__ ow2, const float* __restrict__ ob2,
    float* __restrict__ out)
{
    __shared__ float s_ew1r[3 * 64];
    __shared__ float s_ew2[64 * 64];
    __shared__ float s_ow1[160 * 64];
    __shared__ float s_ow2[64 * 64];
    __shared__ float s_eg1[64], s_ebt1[64], s_eb2[64];
    __shared__ float s_ob1[64], s_og1[64], s_obt1[64], s_ob2[64];
    __shared__ float4 s_rxm[WPB][MT * KNN];    // rx,ry,rz,mean  (32 KB)
    __shared__ float  s_istd[WPB][MT * KNN];   // 8 KB

    const int tid = threadIdx.x;
    for (int t = tid; t < 3 * 64;  t += MLP_BLOCK) s_ew1r[t] = ew1[32 * 64 + t];
    for (int t = tid; t < 64 * 64; t += MLP_BLOCK) s_ew2[t]  = ew2[t];
    for (int t = tid; t < 160 * 64; t += MLP_BLOCK) s_ow1[t] = ow1[t];
    for (int t = tid; t < 64 * 64; t += MLP_BLOCK) s_ow2[t]  = ow2[t];
    if (tid < 64) {
        s_eg1[tid] = eg1[tid];  s_ebt1[tid] = ebt1[tid]; s_eb2[tid] = eb2[tid];
        s_ob1[tid] = ob1[tid];  s_og1[tid] = og1[tid];
        s_obt1[tid] = obt1[tid]; s_ob2[tid] = ob2[tid];
    }
    __syncthreads();

    const int lane = tid & 63;
    const int wave = tid >> 6;
    const int c    = lane;
    const int grp  = blockIdx.x * WPB + wave;
    const int m0   = __builtin_amdgcn_readfirstlane(grp * MT);

    const float Ws0 = cst[0], Ws1 = cst[1], Ws2 = cst[2];
    const float Gxx = cst[3], Gyy = cst[4], Gzz = cst[5];
    const float Gxy = cst[6], Gxz = cst[7], Gyz = cst[8];
    const float inv64 = 1.0f / 64.0f;

    // ---- Phase 1: per-pair LN stats, one (p,j) pair per lane, 2 rounds ----
#pragma unroll
    for (int r = 0; r < 2; ++r) {
        int id = r * 64 + lane;              // 0..127
        int p  = id >> 4, j = id & 15;
        int n  = knn_idx[m0 * KNN + id];     // == (m0+p)*KNN + j, coalesced
        float S1  = aux[n * 8 + 0], Q = aux[n * 8 + 1];
        float P1x = aux[n * 8 + 2], P1y = aux[n * 8 + 3], P1z = aux[n * 8 + 4];
        float rx = verts[n * 3 + 0] - grid_verts[(m0 + p) * 3 + 0];
        float ry = verts[n * 3 + 1] - grid_verts[(m0 + p) * 3 + 1];
        float rz = verts[n * 3 + 2] - grid_verts[(m0 + p) * 3 + 2];
        float s1 = S1 + rx * Ws0 + ry * Ws1 + rz * Ws2;
        float s2 = Q + 2.0f * (rx * P1x + ry * P1y + rz * P1z)
                 + rx * rx * Gxx + ry * ry * Gyy + rz * rz * Gzz
                 + 2.0f * (rx * ry * Gxy + rx * rz * Gxz + ry * rz * Gyz);
        float mean = s1 * inv64;
        float var  = s2 * inv64 - mean * mean;
        float istd = rsqrtf(var + 1e-5f);
        s_rxm[wave][id]  = make_float4(rx, ry, rz, mean);
        s_istd[wave][id] = istd;
    }
    __syncthreads();   // (per-wave region; barrier is belt-and-braces, cheap)

    // ---- Phase 2: channel loop (17 ops/iter vs R13's ~55) ----
    float gsum[MT];
#pragma unroll
    for (int p = 0; p < MT; ++p) gsum[p] = 0.0f;

    for (int p = 0; p < MT; ++p) {
        for (int j = 0; j < KNN; ++j) {
            int n = __builtin_amdgcn_readfirstlane(knn_idx[(m0 + p) * KNN + j]);
            float4 rxm = s_rxm[wave][p * KNN + j];
            float istd = s_istd[wave][p * KNN + j];
            float hv = pre[(size_t)n * COUT + c];
            hv = fmaf(rxm.x, s_ew1r[0 * 64 + c], hv);
            hv = fmaf(rxm.y, s_ew1r[1 * 64 + c], hv);
            hv = fmaf(rxm.z, s_ew1r[2 * 64 + c], hv);
            float xn = (hv - rxm.w) * istd;
            gsum[p] += gelu_fast(xn * s_eg1[c] + s_ebt1[c]);
        }
    }

    float A[MT];
#pragma unroll
    for (int p = 0; p < MT; ++p) { gsum[p] *= (1.0f / 16.0f); A[p] = s_eb2[c]; }
    for (int jj = 0; jj < 64; ++jj) {
        float w = s_ew2[jj * 64 + c];
#pragma unroll
        for (int p = 0; p < MT; ++p)
            A[p] = fmaf(lane_bcast(gsum[p], jj), w, A[p]);
    }

    float gfa[MT], gfb[MT];
#pragma unroll
    for (int p = 0; p < MT; ++p) {
        gfa[p] = grid_feat[(size_t)(m0 + p) * CPROV + c];
        gfb[p] = grid_feat[(size_t)(m0 + p) * CPROV + 64 + (c & 31)];
    }
    float t1[MT];
#pragma unroll
    for (int p = 0; p < MT; ++p) t1[p] = s_ob1[c];
    for (int jj = 0; jj < 64; ++jj) {
        float w = s_ow1[jj * 64 + c];
#pragma unroll
        for (int p = 0; p < MT; ++p)
            t1[p] = fmaf(lane_bcast(A[p], jj), w, t1[p]);
    }
    for (int i = 0; i < 64; ++i) {
        float w = s_ow1[(64 + i) * 64 + c];
#pragma unroll
        for (int p = 0; p < MT; ++p)
            t1[p] = fmaf(lane_bcast(gfa[p], i), w, t1[p]);
    }
    for (int i = 0; i < 32; ++i) {
        float w = s_ow1[(128 + i) * 64 + c];
#pragma unroll
        for (int p = 0; p < MT; ++p)
            t1[p] = fmaf(lane_bcast(gfb[p], i), w, t1[p]);
    }

#pragma unroll
    for (int p = 0; p < MT; ++p) {
        float x = t1[p];
        float s = x, s2 = x * x;
#pragma unroll
        for (int off = 32; off; off >>= 1) {
            s  += __shfl_xor(s, off);
            s2 += __shfl_xor(s2, off);
        }
        float mean = s * inv64;
        float var  = s2 * inv64 - mean * mean;
        float xn = (x - mean) * rsqrtf(var + 1e-5f);
        t1[p] = gelu_fast(xn * s_og1[c] + s_obt1[c]);
    }

    float o[MT];
#pragma unroll
    for (int p = 0; p < MT; ++p) o[p] = s_ob2[c];
    for (int jj = 0; jj < 64; ++jj) {
        float w = s_ow2[jj * 64 + c];
#pragma unroll
        for (int p = 0; p < MT; ++p)
            o[p] = fmaf(lane_bcast(t1[p], jj), w, o[p]);
    }
#pragma unroll
    for (int p = 0; p < MT; ++p)
        out[(size_t)(m0 + p) * COUT + c] = o[p];
}

// ---------------------------------------------------------------------------
extern "C" void kernel_launch(void* const* d_in, const int* in_sizes, int n_in,
                              void* d_out, int out_size, void* d_ws, size_t ws_size,
                              hipStream_t stream)
{
    const float* verts  = (const float*)d_in[0];
    const float* feats  = (const float*)d_in[1];
    const float* gverts = (const float*)d_in[2];
    const float* gfeat  = (const float*)d_in[3];
    const float* ew1    = (const float*)d_in[4];
    const float* eb1    = (const float*)d_in[5];
    const float* eg1    = (const float*)d_in[6];
    const float* ebt1   = (const float*)d_in[7];
    const float* ew2    = (const float*)d_in[8];
    const float* eb2    = (const float*)d_in[9];
    const float* ow1    = (const float*)d_in[10];
    const float* ob1    = (const float*)d_in[11];
    const float* og1    = (const float*)d_in[12];
    const float* obt1   = (const float*)d_in[13];
    const float* ow2    = (const float*)d_in[14];
    const float* ob2    = (const float*)d_in[15];
    float* out = (float*)d_out;

    char* ws = (char*)d_ws;
    int*    counts  = (int*)(ws + 0);              // 128 KB
    int*    prefix  = (int*)(ws + 131072);         // 32769 ints
    float*  tau     = (float*)(ws + 262152);       // 128 KB
    int*    knn_idx = (int*)(ws + 393224);         // 2 MB -> ends 2490376
    unsigned long long* cand = (unsigned long long*)(ws + 2490376);
    // pre/aux/cst overlay cand (dead after knn_merge)
    float*  pre     = (float*)(ws + 2490376);      // 2 MB
    float*  aux     = (float*)(ws + 4587528);      // 256 KB
    float*  cst     = (float*)(ws + 4849672);      // 64 B

    // 16 chunks when cand (NM*16*KNN*8 = 33.5 MB) fits in ws; else proven 4.
    const size_t need16 = 2490376 + (size_t)NM * 16 * KNN * 8;
    const int nch = (ws_size >= need16) ? 16 : 4;

    hipMemsetAsync(counts, 0, 32768 * sizeof(int), stream);
    bin_count_kernel<<<NV / 256, 256, 0, stream>>>(verts, counts);
    prefix_kernel<<<1, 1024, 0, stream>>>(counts, prefix);
    radius_kernel<<<NM / 256, 256, 0, stream>>>(gverts, prefix, tau);
    knn_partial_kernel<<<dim3(NM / 256, nch), 256, 0, stream>>>(verts, gverts, tau, cand);
    knn_merge_kernel<<<NM / 256, 256, 0, stream>>>(cand, knn_idx, nch);
    pre_edge_kernel<<<(NV * COUT) / 256, 256, 0, stream>>>(feats, ew1, eb1, pre, aux);
    const_kernel<<<1, 64, 0, stream>>>(ew1, cst);
    mlp_kernel<<<NM / (MT * WPB), MLP_BLOCK, 0, stream>>>(verts, gverts, gfeat,
        pre, aux, cst, knn_idx,
        ew1, eg1, ebt1, ew2, eb2, ow1, ob1, og1, obt1, ow2, ob2, out);
}